// Round 11
// baseline (453.885 us; speedup 1.0000x reference)
//
#include <hip/hip_runtime.h>

// HydraBackbonePlus: 10 dilations x {X, diffX} x 32 groups, 9-tap grouped dilated
// conv (8 out-ch per group), per-position argmax/argmin over 8 channels,
// histogram-reduced to (32, 1280, 8) with relu.
//
// R11 vs R10 (428us, occupancy 43%, suspected latency-bound: static VALU count
// ~165us vs 405us "busy" -- VALUBusy derived formula likely SIMD-16 fallback):
//  - f16 LDS tiles: Xs 39->18.6KB, total 26.8KB -> 6 blocks/CU (75% occ cap).
//    ldsum via v_pk_add_f16; E/O packs free (even pairs = dwords of the
//    loaded h8 regs, odd pairs = v_alignbit). One extra f16 rounding in the
//    6-channel sum (noise vs threshold).
//  - st-loop strides 8 positions, rolling 16-half window (a,b) + nb PREFETCHED
//    at loop top: ds_read latency spans a full compute body. Halo 16 so the
//    prefetch overrun stays in-bounds (SR = TM+16).
//  - conv = 5 fdot2/ch, 9th tap in a zero-padded 5th weight pair (no f32 tail).
// Commit machinery unchanged from R10 (per-thread LDS cmx slots, u64 cmn).

typedef __fp16 h2_t __attribute__((ext_vector_type(2)));
typedef _Float16 f16x8 __attribute__((ext_vector_type(8)));

#define NB    32
#define CIN   12
#define SEQ   8192
#define NG    32
#define CPER  6
#define OUTCH 1280
#define XS_HALVES 9312   // max over DI of CIN*CS (DI4-8: 12*776)
#define GRID  10240      // 20 (di,j) * 32 b * 16 chunks

template <int DI>
__device__ __forceinline__ void hydra_body(
    const float* __restrict__ X, const float* __restrict__ W,
    const int* __restrict__ I, float* __restrict__ out,
    _Float16* Xs, float* Smx, int j, int b, int chunk) {

  constexpr int d   = 1 << DI;
  constexpr int R   = (d < 16) ? d : 16;       // residues per tile row-set
  constexpr int rb  = (DI < 4) ? DI : 4;       // log2(R)
  constexpr int Mm  = SEQ / d;                 // m-extent of a residue
  constexpr int TMc = 512 / R;
  constexpr int TM  = (TMc < Mm) ? TMc : Mm;   // m per tile (DI=9 -> 16)
  constexpr int MC  = Mm / TM;
  constexpr int RC  = d / R;
  constexpr int NR  = (RC * MC) / 16;          // chunks per block: 1 (DI<9), 2 (DI=9)
  constexpr int SR  = TM + 16;                 // row stride in halves (halo 16, %8==0)
  constexpr int CS  = R * SR + 8;              // channel stride in halves (%8==0)
  constexpr int CL  = (R >= 8) ? TM : (TM * R / 8);  // m per thread per rep
  constexpr int REP = (R == 16) ? 2 : 1;

  const int L = SEQ - j;
  const int tid = threadIdx.x;
  const int g = tid >> 3, s = tid & 7;

  // weights: 8 out-ch x 5 h2 pairs (taps 0..8 + zero pad) = 40 regs
  h2_t Wp[8][5];
  {
    const float* wp = W + (size_t)((DI * 2 + j) * 256 + g * 8) * 9;
#pragma unroll
    for (int k = 0; k < 8; ++k) {
#pragma unroll
      for (int t = 0; t < 4; ++t)
        Wp[k][t] = __builtin_amdgcn_cvt_pkrtz(wp[k * 9 + 2 * t], wp[k * 9 + 2 * t + 1]);
      Wp[k][4] = __builtin_amdgcn_cvt_pkrtz(wp[k * 9 + 8], 0.f);
    }
  }
  const _Float16* base[CPER];
  {
    const int* ip = I + ((DI * 2 + j) * NG + g) * CPER;
#pragma unroll
    for (int i = 0; i < CPER; ++i) base[i] = Xs + ip[i] * CS;
  }

  // zero the per-thread cmx slots (covered by the staging __syncthreads)
#pragma unroll
  for (int k = 0; k < 8; ++k) Smx[k * 256 + tid] = 0.f;

  // cmn: 8 bins as packed u8 lanes of one u64 (counts <= 64/thread)
  unsigned long long cmnp = 0ull;

  for (int n = 0; n < NR; ++n) {
    const int cidx = chunk + 16 * n;
    const int rc = cidx & (RC - 1);
    const int mc = cidx / RC;
    const int r0 = rc * R;
    const int m0 = mc * TM;

    if (NR > 1 && n) __syncthreads();

    // ---- stage 12-channel tile into LDS as f16, zero-padded ----
    {
      const float* xb0 = X + (size_t)b * CIN * SEQ;
      if (j == 0) {
        for (int f = tid; f < R * SR; f += 256) {
          int rr = f & (R - 1), mm = f >> rb, mp = m0 + mm - 4;
          int pos = r0 + rr + mp * d;
          bool ok = (mp >= 0) && (mm < TM + 8) && (pos < L);
          int lo = rr * SR + mm;
          const float* xp = xb0 + pos;
#pragma unroll
          for (int ch = 0; ch < CIN; ++ch) {
            Xs[ch * CS + lo] = ok ? (_Float16)xp[0] : (_Float16)0.f;
            xp += SEQ;
          }
        }
      } else {
        for (int f = tid; f < R * SR; f += 256) {
          int rr = f & (R - 1), mm = f >> rb, mp = m0 + mm - 4;
          int pos = r0 + rr + mp * d;
          bool ok = (mp >= 0) && (mm < TM + 8) && (pos < L);
          int lo = rr * SR + mm;
          const float* xp = xb0 + pos;
#pragma unroll
          for (int ch = 0; ch < CIN; ++ch) {
            Xs[ch * CS + lo] = ok ? (_Float16)(xp[1] - xp[0]) : (_Float16)0.f;
            xp += SEQ;
          }
        }
      }
    }
    __syncthreads();

    // ---- compute: rolling 16-half window, prefetch 8 ahead, dot2 conv ----
#pragma unroll
    for (int rep = 0; rep < REP; ++rep) {
      int rr = (R == 16) ? (s + (rep << 3)) : (s & (R - 1));
      int mst = (R >= 8) ? 0 : ((s >> rb) * CL);
      int rowoff = rr * SR + mst;

      auto sum8 = [&](int idx) {
        f16x8 r = *reinterpret_cast<const f16x8*>(base[0] + idx);
#pragma unroll
        for (int i = 1; i < CPER; ++i)
          r = r + *reinterpret_cast<const f16x8*>(base[i] + idx);
        return r;
      };

      f16x8 a = sum8(rowoff);
      f16x8 bw = sum8(rowoff + 8);
#pragma unroll 1
      for (int st = 0; st < CL; st += 8) {
        f16x8 nb = sum8(rowoff + st + 16);   // prefetch next iter (halo-safe)
        int wv[9];
        {
          int4 ai = __builtin_bit_cast(int4, a);
          int4 bi = __builtin_bit_cast(int4, bw);
          wv[0] = ai.x; wv[1] = ai.y; wv[2] = ai.z; wv[3] = ai.w;
          wv[4] = bi.x; wv[5] = bi.y; wv[6] = bi.z; wv[7] = bi.w;
          wv[8] = ai.x;  // garbage hi for O[7]; multiplied by zero weight
        }
        h2_t E[8], O[8];
#pragma unroll
        for (int i = 0; i < 8; ++i) {
          E[i] = __builtin_bit_cast(h2_t, wv[i]);
          O[i] = __builtin_bit_cast(h2_t,
                   (int)__builtin_amdgcn_alignbit((unsigned)wv[i + 1],
                                                  (unsigned)wv[i], 16));
        }
#pragma unroll
        for (int p = 0; p < 8; ++p) {
          // pairs for taps: even p -> E[p/2+t], odd p -> O[(p-1)/2+t]
          h2_t pr[5];
#pragma unroll
          for (int t = 0; t < 5; ++t)
            pr[t] = (p & 1) ? O[((p - 1) >> 1) + t] : E[(p >> 1) + t];
          float zp[8];
#pragma unroll
          for (int k = 0; k < 8; ++k) {
            float acc = 0.f;
            acc = __builtin_amdgcn_fdot2(Wp[k][4], pr[4], acc, false);
            acc = __builtin_amdgcn_fdot2(Wp[k][3], pr[3], acc, false);
            acc = __builtin_amdgcn_fdot2(Wp[k][2], pr[2], acc, false);
            acc = __builtin_amdgcn_fdot2(Wp[k][1], pr[1], acc, false);
            acc = __builtin_amdgcn_fdot2(Wp[k][0], pr[0], acc, false);
            zp[k] = __uint_as_float((__float_as_uint(acc) & 0xFFFFFFF8u) | (unsigned)k);
          }
          float mxp = fmaxf(fmaxf(fmaxf(zp[0], zp[1]), fmaxf(zp[2], zp[3])),
                            fmaxf(fmaxf(zp[4], zp[5]), fmaxf(zp[6], zp[7])));
          float mnp = fminf(fminf(fminf(zp[0], zp[1]), fminf(zp[2], zp[3])),
                            fminf(fminf(zp[4], zp[5]), fminf(zp[6], zp[7])));
          // cmx: contention-free per-thread LDS slot RMW (no atomic)
          unsigned mxb = __float_as_uint(mxp);
          Smx[((mxb & 7u) << 8) + tid] += mxp;   // tagged val: <=8 ulp bias
          // cmn: packed-byte histogram in a u64 register
          unsigned mnb = __float_as_uint(mnp);
          cmnp += 1ull << ((mnb & 7u) << 3);
        }
        a = bw; bw = nb;
      }
    }
  }

  __syncthreads();

  // ---- flush ----
  {
    int cbase = (DI * 2 + j) * 64;
    // cmx: thread (g,s) sums bin=s over its 8 member threads
    float sum = 0.f;
#pragma unroll
    for (int s2 = 0; s2 < 8; ++s2) sum += Smx[(s << 8) + (g << 3) + s2];
    atomicAdd(out + ((size_t)b * OUTCH + cbase + g) * 8 + s, sum);

    // cmn: unpack bytes, butterfly over the 8 s-lanes, lane s commits bin s
    int cnts[8];
#pragma unroll
    for (int k = 0; k < 8; ++k) cnts[k] = (int)((cmnp >> (k * 8)) & 0xFFull);
#pragma unroll
    for (int k = 0; k < 8; ++k) {
#pragma unroll
      for (int off = 1; off < 8; off <<= 1)
        cnts[k] += __shfl_xor(cnts[k], off);
    }
    int vn = cnts[0];
#pragma unroll
    for (int k = 1; k < 8; ++k) vn = (s == k) ? cnts[k] : vn;
    atomicAdd(out + ((size_t)b * OUTCH + cbase + 32 + g) * 8 + s, (float)vn);
  }
}

__global__ __launch_bounds__(256, 3) void hydra_fused(
    const float* __restrict__ X, const float* __restrict__ W,
    const int* __restrict__ I, float* __restrict__ out) {
  __shared__ _Float16 Xs[XS_HALVES];
  __shared__ float Smx[2048];   // 8 bins x 256 threads
  int u = blockIdx.x;
  int dj = u % 20;            // consecutive blocks interleave (di,j)
  int rest = u / 20;
  int b = rest & 31;
  int chunk = rest >> 5;
  int j = dj & 1;
  switch (dj >> 1) {
    case 0: hydra_body<0>(X, W, I, out, Xs, Smx, j, b, chunk); break;
    case 1: hydra_body<1>(X, W, I, out, Xs, Smx, j, b, chunk); break;
    case 2: hydra_body<2>(X, W, I, out, Xs, Smx, j, b, chunk); break;
    case 3: hydra_body<3>(X, W, I, out, Xs, Smx, j, b, chunk); break;
    case 4: hydra_body<4>(X, W, I, out, Xs, Smx, j, b, chunk); break;
    case 5: hydra_body<5>(X, W, I, out, Xs, Smx, j, b, chunk); break;
    case 6: hydra_body<6>(X, W, I, out, Xs, Smx, j, b, chunk); break;
    case 7: hydra_body<7>(X, W, I, out, Xs, Smx, j, b, chunk); break;
    case 8: hydra_body<8>(X, W, I, out, Xs, Smx, j, b, chunk); break;
    case 9: hydra_body<9>(X, W, I, out, Xs, Smx, j, b, chunk); break;
  }
}

__global__ void hydra_relu(float* __restrict__ out, int n) {
  int i = blockIdx.x * 256 + threadIdx.x;
  if (i < n) out[i] = fmaxf(out[i], 0.f);
}

extern "C" void kernel_launch(void* const* d_in, const int* in_sizes, int n_in,
                              void* d_out, int out_size, void* d_ws, size_t ws_size,
                              hipStream_t stream) {
  const float* X = (const float*)d_in[0];
  const float* W = (const float*)d_in[1];
  const int*   I = (const int*)d_in[2];
  float* out = (float*)d_out;

  (void)hipMemsetAsync(d_out, 0, (size_t)out_size * sizeof(float), stream);
  hydra_fused<<<GRID, 256, 0, stream>>>(X, W, I, out);
  hydra_relu<<<(out_size + 255) / 256, 256, 0, stream>>>(out, out_size);
}

// Round 12
// 453.505 us; speedup vs baseline: 1.0008x; 1.0008x over previous
//
#include <hip/hip_runtime.h>

// HydraBackbonePlus: 10 dilations x {X, diffX} x 32 groups, 9-tap grouped dilated
// conv (8 out-ch per group), per-position argmax/argmin over 8 channels,
// histogram-reduced to (32, 1280, 8) with relu.
//
// R12 vs R11 (single change): __attribute__((amdgpu_waves_per_eu(4,4))).
// R7-R11 all landed VGPR 60-64: the compiler squeezes to the 8-waves/EU
// boundary and REMATERIALIZES (re-loads weights from global per iteration --
// Wp alone is 40 VGPRs > the 60 allocated) since LDS caps us at 4-6 blocks/CU
// anyway. Pinning waves/EU to 4 gives a 128-reg budget: live set (~100) fits
// with zero remat and zero scratch. Canary: VGPR_Count must rise to ~90-128.

typedef __fp16 h2_t __attribute__((ext_vector_type(2)));
typedef _Float16 f16x8 __attribute__((ext_vector_type(8)));

#define NB    32
#define CIN   12
#define SEQ   8192
#define NG    32
#define CPER  6
#define OUTCH 1280
#define XS_HALVES 9312   // max over DI of CIN*CS (DI4-8: 12*776)
#define GRID  10240      // 20 (di,j) * 32 b * 16 chunks

template <int DI>
__device__ __forceinline__ void hydra_body(
    const float* __restrict__ X, const float* __restrict__ W,
    const int* __restrict__ I, float* __restrict__ out,
    _Float16* Xs, float* Smx, int j, int b, int chunk) {

  constexpr int d   = 1 << DI;
  constexpr int R   = (d < 16) ? d : 16;       // residues per tile row-set
  constexpr int rb  = (DI < 4) ? DI : 4;       // log2(R)
  constexpr int Mm  = SEQ / d;                 // m-extent of a residue
  constexpr int TMc = 512 / R;
  constexpr int TM  = (TMc < Mm) ? TMc : Mm;   // m per tile (DI=9 -> 16)
  constexpr int MC  = Mm / TM;
  constexpr int RC  = d / R;
  constexpr int NR  = (RC * MC) / 16;          // chunks per block: 1 (DI<9), 2 (DI=9)
  constexpr int SR  = TM + 16;                 // row stride in halves (halo 16, %8==0)
  constexpr int CS  = R * SR + 8;              // channel stride in halves (%8==0)
  constexpr int CL  = (R >= 8) ? TM : (TM * R / 8);  // m per thread per rep
  constexpr int REP = (R == 16) ? 2 : 1;

  const int L = SEQ - j;
  const int tid = threadIdx.x;
  const int g = tid >> 3, s = tid & 7;

  // weights: 8 out-ch x 5 h2 pairs (taps 0..8 + zero pad) = 40 regs
  h2_t Wp[8][5];
  {
    const float* wp = W + (size_t)((DI * 2 + j) * 256 + g * 8) * 9;
#pragma unroll
    for (int k = 0; k < 8; ++k) {
#pragma unroll
      for (int t = 0; t < 4; ++t)
        Wp[k][t] = __builtin_amdgcn_cvt_pkrtz(wp[k * 9 + 2 * t], wp[k * 9 + 2 * t + 1]);
      Wp[k][4] = __builtin_amdgcn_cvt_pkrtz(wp[k * 9 + 8], 0.f);
    }
  }
  const _Float16* base[CPER];
  {
    const int* ip = I + ((DI * 2 + j) * NG + g) * CPER;
#pragma unroll
    for (int i = 0; i < CPER; ++i) base[i] = Xs + ip[i] * CS;
  }

  // zero the per-thread cmx slots (covered by the staging __syncthreads)
#pragma unroll
  for (int k = 0; k < 8; ++k) Smx[k * 256 + tid] = 0.f;

  // cmn: 8 bins as packed u8 lanes of one u64 (counts <= 64/thread)
  unsigned long long cmnp = 0ull;

  for (int n = 0; n < NR; ++n) {
    const int cidx = chunk + 16 * n;
    const int rc = cidx & (RC - 1);
    const int mc = cidx / RC;
    const int r0 = rc * R;
    const int m0 = mc * TM;

    if (NR > 1 && n) __syncthreads();

    // ---- stage 12-channel tile into LDS as f16, zero-padded ----
    {
      const float* xb0 = X + (size_t)b * CIN * SEQ;
      if (j == 0) {
        for (int f = tid; f < R * SR; f += 256) {
          int rr = f & (R - 1), mm = f >> rb, mp = m0 + mm - 4;
          int pos = r0 + rr + mp * d;
          bool ok = (mp >= 0) && (mm < TM + 8) && (pos < L);
          int lo = rr * SR + mm;
          const float* xp = xb0 + pos;
#pragma unroll
          for (int ch = 0; ch < CIN; ++ch) {
            Xs[ch * CS + lo] = ok ? (_Float16)xp[0] : (_Float16)0.f;
            xp += SEQ;
          }
        }
      } else {
        for (int f = tid; f < R * SR; f += 256) {
          int rr = f & (R - 1), mm = f >> rb, mp = m0 + mm - 4;
          int pos = r0 + rr + mp * d;
          bool ok = (mp >= 0) && (mm < TM + 8) && (pos < L);
          int lo = rr * SR + mm;
          const float* xp = xb0 + pos;
#pragma unroll
          for (int ch = 0; ch < CIN; ++ch) {
            Xs[ch * CS + lo] = ok ? (_Float16)(xp[1] - xp[0]) : (_Float16)0.f;
            xp += SEQ;
          }
        }
      }
    }
    __syncthreads();

    // ---- compute: rolling 16-half window, prefetch 8 ahead, dot2 conv ----
#pragma unroll
    for (int rep = 0; rep < REP; ++rep) {
      int rr = (R == 16) ? (s + (rep << 3)) : (s & (R - 1));
      int mst = (R >= 8) ? 0 : ((s >> rb) * CL);
      int rowoff = rr * SR + mst;

      auto sum8 = [&](int idx) {
        f16x8 r = *reinterpret_cast<const f16x8*>(base[0] + idx);
#pragma unroll
        for (int i = 1; i < CPER; ++i)
          r = r + *reinterpret_cast<const f16x8*>(base[i] + idx);
        return r;
      };

      f16x8 a = sum8(rowoff);
      f16x8 bw = sum8(rowoff + 8);
#pragma unroll 1
      for (int st = 0; st < CL; st += 8) {
        f16x8 nb = sum8(rowoff + st + 16);   // prefetch next iter (halo-safe)
        int wv[9];
        {
          int4 ai = __builtin_bit_cast(int4, a);
          int4 bi = __builtin_bit_cast(int4, bw);
          wv[0] = ai.x; wv[1] = ai.y; wv[2] = ai.z; wv[3] = ai.w;
          wv[4] = bi.x; wv[5] = bi.y; wv[6] = bi.z; wv[7] = bi.w;
          wv[8] = ai.x;  // garbage hi for O[7]; multiplied by zero weight
        }
        h2_t E[8], O[8];
#pragma unroll
        for (int i = 0; i < 8; ++i) {
          E[i] = __builtin_bit_cast(h2_t, wv[i]);
          O[i] = __builtin_bit_cast(h2_t,
                   (int)__builtin_amdgcn_alignbit((unsigned)wv[i + 1],
                                                  (unsigned)wv[i], 16));
        }
#pragma unroll
        for (int p = 0; p < 8; ++p) {
          // pairs for taps: even p -> E[p/2+t], odd p -> O[(p-1)/2+t]
          h2_t pr[5];
#pragma unroll
          for (int t = 0; t < 5; ++t)
            pr[t] = (p & 1) ? O[((p - 1) >> 1) + t] : E[(p >> 1) + t];
          float zp[8];
#pragma unroll
          for (int k = 0; k < 8; ++k) {
            float acc = 0.f;
            acc = __builtin_amdgcn_fdot2(Wp[k][4], pr[4], acc, false);
            acc = __builtin_amdgcn_fdot2(Wp[k][3], pr[3], acc, false);
            acc = __builtin_amdgcn_fdot2(Wp[k][2], pr[2], acc, false);
            acc = __builtin_amdgcn_fdot2(Wp[k][1], pr[1], acc, false);
            acc = __builtin_amdgcn_fdot2(Wp[k][0], pr[0], acc, false);
            zp[k] = __uint_as_float((__float_as_uint(acc) & 0xFFFFFFF8u) | (unsigned)k);
          }
          float mxp = fmaxf(fmaxf(fmaxf(zp[0], zp[1]), fmaxf(zp[2], zp[3])),
                            fmaxf(fmaxf(zp[4], zp[5]), fmaxf(zp[6], zp[7])));
          float mnp = fminf(fminf(fminf(zp[0], zp[1]), fminf(zp[2], zp[3])),
                            fminf(fminf(zp[4], zp[5]), fminf(zp[6], zp[7])));
          // cmx: contention-free per-thread LDS slot RMW (no atomic)
          unsigned mxb = __float_as_uint(mxp);
          Smx[((mxb & 7u) << 8) + tid] += mxp;   // tagged val: <=8 ulp bias
          // cmn: packed-byte histogram in a u64 register
          unsigned mnb = __float_as_uint(mnp);
          cmnp += 1ull << ((mnb & 7u) << 3);
        }
        a = bw; bw = nb;
      }
    }
  }

  __syncthreads();

  // ---- flush ----
  {
    int cbase = (DI * 2 + j) * 64;
    // cmx: thread (g,s) sums bin=s over its 8 member threads
    float sum = 0.f;
#pragma unroll
    for (int s2 = 0; s2 < 8; ++s2) sum += Smx[(s << 8) + (g << 3) + s2];
    atomicAdd(out + ((size_t)b * OUTCH + cbase + g) * 8 + s, sum);

    // cmn: unpack bytes, butterfly over the 8 s-lanes, lane s commits bin s
    int cnts[8];
#pragma unroll
    for (int k = 0; k < 8; ++k) cnts[k] = (int)((cmnp >> (k * 8)) & 0xFFull);
#pragma unroll
    for (int k = 0; k < 8; ++k) {
#pragma unroll
      for (int off = 1; off < 8; off <<= 1)
        cnts[k] += __shfl_xor(cnts[k], off);
    }
    int vn = cnts[0];
#pragma unroll
    for (int k = 1; k < 8; ++k) vn = (s == k) ? cnts[k] : vn;
    atomicAdd(out + ((size_t)b * OUTCH + cbase + 32 + g) * 8 + s, (float)vn);
  }
}

__global__ __launch_bounds__(256)
__attribute__((amdgpu_waves_per_eu(4, 4)))
void hydra_fused(
    const float* __restrict__ X, const float* __restrict__ W,
    const int* __restrict__ I, float* __restrict__ out) {
  __shared__ _Float16 Xs[XS_HALVES];
  __shared__ float Smx[2048];   // 8 bins x 256 threads
  int u = blockIdx.x;
  int dj = u % 20;            // consecutive blocks interleave (di,j)
  int rest = u / 20;
  int b = rest & 31;
  int chunk = rest >> 5;
  int j = dj & 1;
  switch (dj >> 1) {
    case 0: hydra_body<0>(X, W, I, out, Xs, Smx, j, b, chunk); break;
    case 1: hydra_body<1>(X, W, I, out, Xs, Smx, j, b, chunk); break;
    case 2: hydra_body<2>(X, W, I, out, Xs, Smx, j, b, chunk); break;
    case 3: hydra_body<3>(X, W, I, out, Xs, Smx, j, b, chunk); break;
    case 4: hydra_body<4>(X, W, I, out, Xs, Smx, j, b, chunk); break;
    case 5: hydra_body<5>(X, W, I, out, Xs, Smx, j, b, chunk); break;
    case 6: hydra_body<6>(X, W, I, out, Xs, Smx, j, b, chunk); break;
    case 7: hydra_body<7>(X, W, I, out, Xs, Smx, j, b, chunk); break;
    case 8: hydra_body<8>(X, W, I, out, Xs, Smx, j, b, chunk); break;
    case 9: hydra_body<9>(X, W, I, out, Xs, Smx, j, b, chunk); break;
  }
}

__global__ void hydra_relu(float* __restrict__ out, int n) {
  int i = blockIdx.x * 256 + threadIdx.x;
  if (i < n) out[i] = fmaxf(out[i], 0.f);
}

extern "C" void kernel_launch(void* const* d_in, const int* in_sizes, int n_in,
                              void* d_out, int out_size, void* d_ws, size_t ws_size,
                              hipStream_t stream) {
  const float* X = (const float*)d_in[0];
  const float* W = (const float*)d_in[1];
  const int*   I = (const int*)d_in[2];
  float* out = (float*)d_out;

  (void)hipMemsetAsync(d_out, 0, (size_t)out_size * sizeof(float), stream);
  hydra_fused<<<GRID, 256, 0, stream>>>(X, W, I, out);
  hydra_relu<<<(out_size + 255) / 256, 256, 0, stream>>>(out, out_size);
}